// Round 10
// baseline (900.555 us; speedup 1.0000x reference)
//
#include <hip/hip_runtime.h>
#include <stdint.h>

#define NUM_ENTRIES 1000000
#define NUM_HINTS   32768
#define MAX_SUBSET  512
#define CHUNKS      5
#define ROW_BYTES   20
#define SLICES      8
#define SLICE_BYTES (NUM_ENTRIES / SLICES * ROW_BYTES)   // 2.5 MB, fits 4 MB XCD L2
#define TABLE_BYTES (NUM_ENTRIES * ROW_BYTES)

typedef unsigned u32x4a4 __attribute__((ext_vector_type(4), aligned(4)));

// Phase-sliced gather, spill-free layout:
//   16-lane group owns ONE hint; each lane owns 32 consecutive slots of it.
//   Per-thread state: 32 byte-offsets (validity packed as 0xFFFFFFFF sentinel)
//   + 5 XOR accumulators  ->  ~40 VGPR persistent, fits 64-VGPR cap (8 wg/CU).
//   All co-resident waves sweep slices 0..7; during pass p only slice p
//   (2.5 MB) is gathered -> L2-resident per XCD. Grid = 2048 blocks
//   = 8 blocks/CU -> whole grid is one cohort; indices/mask read exactly once.
__global__ __launch_bounds__(256, 8) void hint_xor_kernel(
    const void* __restrict__ entries_v,
    const void* __restrict__ indices_v,
    const void* __restrict__ mask_v,
    int* __restrict__ out)
{
    const int wave = threadIdx.x >> 6;
    const int lane = threadIdx.x & 63;
    const int sub  = lane & 15;                       // position within 16-lane group
    const int hint = blockIdx.x * 16 + wave * 4 + (lane >> 4);

    // ---- layout detection (wave-uniform votes, FP <= 2^-64) ----
    const unsigned* ew = (const unsigned*)entries_v;
    const unsigned* iw = (const unsigned*)indices_v;
    const unsigned* mw = (const unsigned*)mask_v;
    const unsigned es = ew[lane];
    const unsigned is = iw[lane];
    const unsigned ms = mw[lane];
    const bool odd = (lane & 1) != 0;
    const bool ent32   = __any(odd && (es & 0xC0000000u));
    const bool idx32   = __any(odd && (is != 0u));
    const bool m_bytes = __any((ms != 0u) && (ms != 1u) && (ms != 0x3f800000u));
    const bool m_odd_nz = __any(odd && (ms != 0u));
    const int  mstep = m_odd_nz ? 1 : 2;

    unsigned acc0 = 0, acc1 = 0, acc2 = 0, acc3 = 0, acc4 = 0;

    if (ent32 && idx32 && m_bytes) {
        // ================= fast path (confirmed layouts) =================
        const int*           idxp  = (const int*)indices_v;
        const unsigned char* mp    = (const unsigned char*)mask_v;
        const char*          ebase = (const char*)entries_v;

        // prologue: load 32 indices + 32 mask bytes; pack validity into the
        // offset (invalid -> 0xFFFFFFFF, fails every slice-range test).
        const size_t base = (size_t)hint * MAX_SUBSET + 32u * (unsigned)sub;
        unsigned off[32];
        {
            const u32x4a4 mv0 = __builtin_nontemporal_load((const u32x4a4*)(mp + base));
            const u32x4a4 mv1 = __builtin_nontemporal_load((const u32x4a4*)(mp + base + 16));
            #pragma unroll
            for (int i = 0; i < 8; ++i) {
                const u32x4a4 iv =
                    __builtin_nontemporal_load((const u32x4a4*)(idxp + base + 4 * i));
                #pragma unroll
                for (int c = 0; c < 4; ++c) {
                    const int t = 4 * i + c;
                    const unsigned md = (t < 16) ? mv0[t >> 2] : mv1[(t - 16) >> 2];
                    const unsigned mb = (md >> (8 * (t & 3))) & 0xFFu;
                    off[t] = mb ? iv[c] * 20u : 0xFFFFFFFFu;
                }
            }
        }

        // slice sweep: pass p gathers only from slice p
        #pragma unroll 1
        for (int p = 0; p < SLICES; ++p) {
            const unsigned lo = (unsigned)p * (unsigned)SLICE_BYTES;
            #pragma unroll
            for (int t = 0; t < 32; ++t) {
                const unsigned o = off[t];
                // in-slice test (unsigned wrap) doubles as bounds guard:
                // deref only when o in [lo, lo+SLICE) subset of [0, 20MB)
                if (o - lo < (unsigned)SLICE_BYTES) {
                    const u32x4a4 q = *(const u32x4a4*)(ebase + o);
                    const unsigned w = *(const unsigned*)(ebase + o + 16);
                    acc0 ^= q.x; acc1 ^= q.y; acc2 ^= q.z; acc3 ^= q.w; acc4 ^= w;
                }
            }
        }
    } else {
        // ================= generic fallback (any layout) =================
        const int*           idx32p = (const int*)indices_v;
        const long long*     idx64p = (const long long*)indices_v;
        const unsigned char* m8p    = (const unsigned char*)mask_v;
        const unsigned*      m32p   = (const unsigned*)mask_v;

        const size_t base = (size_t)hint * MAX_SUBSET + 32u * (unsigned)sub;
        #pragma unroll 1
        for (int t = 0; t < 32; ++t) {
            const size_t s = base + (size_t)t;
            long long idx = idx32 ? (long long)idx32p[s] : idx64p[s];
            unsigned mv = m_bytes ? (unsigned)m8p[s] : m32p[s * (size_t)mstep];
            const bool v = (mv != 0u) &&
                           ((unsigned long long)idx < (unsigned long long)NUM_ENTRIES);
            if (v) {
                if (ent32) {
                    const unsigned* e = (const unsigned*)entries_v + (size_t)idx * 5u;
                    acc0 ^= e[0]; acc1 ^= e[1]; acc2 ^= e[2]; acc3 ^= e[3]; acc4 ^= e[4];
                } else {
                    const unsigned* e = (const unsigned*)entries_v + (size_t)idx * 10u;
                    acc0 ^= e[0]; acc1 ^= e[2]; acc2 ^= e[4]; acc3 ^= e[6]; acc4 ^= e[8];
                }
            }
        }
    }

    // XOR reduction within each 16-lane group (masks 1,2,4,8 stay in-group)
    #pragma unroll
    for (int o = 8; o >= 1; o >>= 1) {
        acc0 ^= (unsigned)__shfl_xor((int)acc0, o, 64);
        acc1 ^= (unsigned)__shfl_xor((int)acc1, o, 64);
        acc2 ^= (unsigned)__shfl_xor((int)acc2, o, 64);
        acc3 ^= (unsigned)__shfl_xor((int)acc3, o, 64);
        acc4 ^= (unsigned)__shfl_xor((int)acc4, o, 64);
    }

    // group leader writes its hint's 5-word parity (655 KB total, negligible)
    if (sub == 0) {
        int* o = out + (size_t)hint * CHUNKS;
        o[0] = (int)acc0; o[1] = (int)acc1; o[2] = (int)acc2;
        o[3] = (int)acc3; o[4] = (int)acc4;
    }
}

extern "C" void kernel_launch(void* const* d_in, const int* in_sizes, int n_in,
                              void* d_out, int out_size, void* d_ws, size_t ws_size,
                              hipStream_t stream) {
    const void* entries = d_in[0];
    const void* indices = d_in[1];
    const void* mask    = d_in[2];
    int*        out     = (int*)d_out;

    // 16 hints/block (4 waves x 4 groups) -> 2048 blocks = 8 blocks/CU:
    // whole grid co-resident, one slice-sweep cohort
    hint_xor_kernel<<<NUM_HINTS / 16, 256, 0, stream>>>(entries, indices, mask, out);
}

// Round 11
// 262.948 us; speedup vs baseline: 3.4248x; 3.4248x over previous
//
#include <hip/hip_runtime.h>
#include <stdint.h>

#define NUM_ENTRIES 1000000
#define NUM_HINTS   32768
#define MAX_SUBSET  512
#define CHUNKS      5

typedef unsigned u32x4a4  __attribute__((ext_vector_type(4), aligned(4)));
typedef unsigned u32x4a16 __attribute__((ext_vector_type(4), aligned(16)));

// Round-5 structure (best measured: 151us / 536MB) + max memory-level
// parallelism: all 16 gather loads (8 rows x dwordx4+dword) issued
// back-to-back per wave. Invalid slots gather row 0 (L1-hot, no TCC traffic)
// and are AND-masked out before the XOR -> no divergence, straight-line code,
// compile-time register indexing (no spill).
__global__ __launch_bounds__(256, 8) void hint_xor_kernel(
    const void* __restrict__ entries_v,
    const void* __restrict__ indices_v,
    const void* __restrict__ mask_v,
    int* __restrict__ out)
{
    const int wave = threadIdx.x >> 6;
    const int lane = threadIdx.x & 63;
    const int hint = blockIdx.x * 4 + wave;

    // ---- layout detection (wave-uniform votes, FP <= 2^-64) ----
    const unsigned* ew = (const unsigned*)entries_v;
    const unsigned* iw = (const unsigned*)indices_v;
    const unsigned* mw = (const unsigned*)mask_v;
    const unsigned es = ew[lane];
    const unsigned is = iw[lane];
    const unsigned ms = mw[lane];
    const bool odd = (lane & 1) != 0;
    const bool ent32   = __any(odd && (es & 0xC0000000u));
    const bool idx32   = __any(odd && (is != 0u));
    const bool m_bytes = __any((ms != 0u) && (ms != 1u) && (ms != 0x3f800000u));
    const bool m_odd_nz = __any(odd && (ms != 0u));
    const int  mstep = m_odd_nz ? 1 : 2;

    unsigned acc0 = 0, acc1 = 0, acc2 = 0, acc3 = 0, acc4 = 0;

    if (ent32 && idx32 && m_bytes) {
        // ================= fast path (confirmed layouts) =================
        const int*      idxp = (const int*)indices_v;
        const unsigned* mwp  = (const unsigned*)mask_v;
        const char*     ebase = (const char*)entries_v;
        const size_t    hbase = (size_t)hint * MAX_SUBSET;

        // Lane owns slots {4l..4l+3} u {256+4l..256+4l+3}. Each stream load
        // instruction spans a contiguous 1KB/256B region per wave -> every
        // cache line fetched exactly once even with NT policy.
        const u32x4a16 i0 = __builtin_nontemporal_load((const u32x4a16*)(idxp + hbase) + lane);
        const u32x4a16 i1 = __builtin_nontemporal_load((const u32x4a16*)(idxp + hbase + 256) + lane);
        const unsigned m0 = __builtin_nontemporal_load(mwp + (hbase >> 2) + lane);        // mask bytes 4l..4l+3
        const unsigned m1 = __builtin_nontemporal_load(mwp + (hbase >> 2) + 64 + lane);   // mask bytes 256+4l..

        unsigned off[8], xm[8];
        #pragma unroll
        for (int c = 0; c < 4; ++c) {
            const unsigned b0 = (m0 >> (8 * c)) & 0xFFu;
            const unsigned b1 = (m1 >> (8 * c)) & 0xFFu;
            const unsigned v0 = (unsigned)i0[c];
            const unsigned v1 = (unsigned)i1[c];
            const bool ok0 = b0 && (v0 < (unsigned)NUM_ENTRIES);  // bounds guard
            const bool ok1 = b1 && (v1 < (unsigned)NUM_ENTRIES);
            off[c]     = ok0 ? v0 * 20u : 0u;        // invalid -> row 0 (L1-hot)
            xm[c]      = ok0 ? 0xFFFFFFFFu : 0u;
            off[4 + c] = ok1 ? v1 * 20u : 0u;
            xm[4 + c]  = ok1 ? 0xFFFFFFFFu : 0u;
        }

        // 16 independent gather loads, issued straight-line (max MLP)
        u32x4a4 q[8]; unsigned w[8];
        #pragma unroll
        for (int t = 0; t < 8; ++t) {
            q[t] = *(const u32x4a4*)(ebase + off[t]);
            w[t] = *(const unsigned*)(ebase + off[t] + 16);
        }
        #pragma unroll
        for (int t = 0; t < 8; ++t) {
            acc0 ^= q[t].x & xm[t];
            acc1 ^= q[t].y & xm[t];
            acc2 ^= q[t].z & xm[t];
            acc3 ^= q[t].w & xm[t];
            acc4 ^= w[t]   & xm[t];
        }
    } else {
        // ================= generic fallback (any layout) =================
        const int*           idx32p = (const int*)indices_v;
        const long long*     idx64p = (const long long*)indices_v;
        const unsigned char* m8p    = (const unsigned char*)mask_v;
        const unsigned*      m32p   = (const unsigned*)mask_v;

        const size_t rowoff = (size_t)hint * MAX_SUBSET;
        #pragma unroll 1
        for (int k = 0; k < 8; ++k) {
            const size_t s = rowoff + (size_t)(k * 64 + lane);
            long long idx = idx32 ? (long long)idx32p[s] : idx64p[s];
            unsigned mv = m_bytes ? (unsigned)m8p[s] : m32p[s * (size_t)mstep];
            const bool v = (mv != 0u) &&
                           ((unsigned long long)idx < (unsigned long long)NUM_ENTRIES);
            if (v) {
                if (ent32) {
                    const unsigned* e = (const unsigned*)entries_v + (size_t)idx * 5u;
                    acc0 ^= e[0]; acc1 ^= e[1]; acc2 ^= e[2]; acc3 ^= e[3]; acc4 ^= e[4];
                } else {
                    const unsigned* e = (const unsigned*)entries_v + (size_t)idx * 10u;
                    acc0 ^= e[0]; acc1 ^= e[2]; acc2 ^= e[4]; acc3 ^= e[6]; acc4 ^= e[8];
                }
            }
        }
    }

    // 64-lane XOR butterfly
    #pragma unroll
    for (int o = 32; o >= 1; o >>= 1) {
        acc0 ^= (unsigned)__shfl_xor((int)acc0, o, 64);
        acc1 ^= (unsigned)__shfl_xor((int)acc1, o, 64);
        acc2 ^= (unsigned)__shfl_xor((int)acc2, o, 64);
        acc3 ^= (unsigned)__shfl_xor((int)acc3, o, 64);
        acc4 ^= (unsigned)__shfl_xor((int)acc4, o, 64);
    }

    // coalesced epilogue: lanes 0..4 write one dword each
    if (lane < CHUNKS) {
        unsigned r = acc0;
        r = (lane == 1) ? acc1 : r;
        r = (lane == 2) ? acc2 : r;
        r = (lane == 3) ? acc3 : r;
        r = (lane == 4) ? acc4 : r;
        out[(size_t)hint * CHUNKS + lane] = (int)r;
    }
}

extern "C" void kernel_launch(void* const* d_in, const int* in_sizes, int n_in,
                              void* d_out, int out_size, void* d_ws, size_t ws_size,
                              hipStream_t stream) {
    const void* entries = d_in[0];
    const void* indices = d_in[1];
    const void* mask    = d_in[2];
    int*        out     = (int*)d_out;

    // 4 waves/block, one wave per hint -> 8192 blocks
    hint_xor_kernel<<<NUM_HINTS / 4, 256, 0, stream>>>(entries, indices, mask, out);
}